// Round 1
// baseline (39020.422 us; speedup 1.0000x reference)
//
#include <hip/hip_runtime.h>
#include <math.h>

#define T_LEN 1024
#define BATCH 256
#define IN_DIM 66
#define HID 256
#define TAGS 10
#define NEG_INF -10000.0f
#define START_TAG 8
#define STOP_TAG 9

#define KTOT (HID + IN_DIM)  /* 322 */

/* workspace layout (float offsets) */
#define WS_H     0                             /* [2 dir][2 buf][BATCH][HID] */
#define WS_C     (WS_H + 2 * 2 * BATCH * HID)  /* [2 dir][BATCH][HID]        */
#define WS_FEATS (WS_C + 2 * BATCH * HID)      /* [T][BATCH][TAGS]           */
#define WS_NLL   (WS_FEATS + T_LEN * BATCH * TAGS) /* [BATCH]                */

/* ---------------- init: zero h/c, feats = lin_b broadcast ---------------- */
__global__ void init_kernel(float* __restrict__ ws, const float* __restrict__ lin_b)
{
    const int n_zero = WS_FEATS;                 /* h + c region   */
    const int n_feat = T_LEN * BATCH * TAGS;     /* feats region   */
    const int n_tot = n_zero + n_feat;
    for (int i = blockIdx.x * blockDim.x + threadIdx.x; i < n_tot;
         i += gridDim.x * blockDim.x) {
        if (i < n_zero) ws[i] = 0.0f;
        else            ws[WS_FEATS + (i - n_zero)] = lin_b[(i - n_zero) % TAGS];
    }
}

/* ---------------- one LSTM timestep, both directions ----------------
 * grid = 256 blocks x 256 threads.
 * block: dir = bx>>7, batch-tile bt = (bx>>4)&7 (32 batches), hidden-tile
 * jt = bx&15 (16 hidden units). Thread (tx=tid&15, ty=tid>>4) computes
 * batches {2ty,2ty+1} x hidden j0+tx x all 4 gates.
 * After the gate GEMM: c/h update, h written to ping-pong buffer, and the
 * tile's contribution to feats[t] (h @ lin_w^T) is atomicAdd'ed.
 */
__launch_bounds__(256)
__global__ void lstm_step(const float* __restrict__ feat_in,
                          const float* __restrict__ w_ih_f,
                          const float* __restrict__ w_hh_f,
                          const float* __restrict__ b_f,
                          const float* __restrict__ w_ih_b,
                          const float* __restrict__ w_hh_b,
                          const float* __restrict__ b_b,
                          const float* __restrict__ lin_w,
                          float* __restrict__ ws, int s)
{
    const int bx  = blockIdx.x;
    const int dir = bx >> 7;
    const int bt  = (bx >> 4) & 7;
    const int jt  = bx & 15;
    const int b0  = bt * 32;
    const int j0  = jt * 16;

    const float* w_ih = dir ? w_ih_b : w_ih_f;
    const float* w_hh = dir ? w_hh_b : w_hh_f;
    const float* bias = dir ? b_b    : b_f;
    const int t = dir ? (T_LEN - 1 - s) : s;

    float* hbuf = ws + WS_H + dir * (2 * BATCH * HID);
    const float* h_prev = hbuf + (s & 1) * (BATCH * HID);
    float* h_new        = hbuf + ((s & 1) ^ 1) * (BATCH * HID);
    float* cbuf  = ws + WS_C + dir * (BATCH * HID);
    float* feats = ws + WS_FEATS;

    __shared__ float As[32][36];       /* batch x k-chunk, padded      */
    __shared__ float Wsh[4][16][36];   /* gate x hidden x k-chunk      */
    __shared__ float hn[32][16];       /* new h tile for feats partial */

    const int tid = threadIdx.x;
    const int tx = tid & 15;
    const int ty = tid >> 4;

    float acc[2][4];
#pragma unroll
    for (int i = 0; i < 2; ++i)
#pragma unroll
        for (int g = 0; g < 4; ++g) acc[i][g] = 0.0f;

    for (int kc = 0; kc < KTOT; kc += 32) {
        /* stage A: h_prev (k<256) then x_t (256<=k<322), zero-pad past 322 */
        for (int idx = tid; idx < 32 * 32; idx += 256) {
            const int r = idx >> 5, c = idx & 31;
            const int k = kc + c;
            float v = 0.0f;
            if (k < HID)        v = h_prev[(b0 + r) * HID + k];
            else if (k < KTOT)  v = feat_in[(t * BATCH + b0 + r) * IN_DIM + (k - HID)];
            As[r][c] = v;
        }
        /* stage W rows for 4 gates x 16 hidden units */
        for (int idx = tid; idx < 4 * 16 * 32; idx += 256) {
            const int g = idx >> 9;
            const int r = (idx >> 5) & 15;
            const int c = idx & 31;
            const int k = kc + c;
            const int row = g * HID + j0 + r;
            float v = 0.0f;
            if (k < HID)        v = w_hh[row * HID + k];
            else if (k < KTOT)  v = w_ih[row * IN_DIM + (k - HID)];
            Wsh[g][r][c] = v;
        }
        __syncthreads();
#pragma unroll
        for (int k4 = 0; k4 < 8; ++k4) {
            const float4 a0 = *(const float4*)&As[2 * ty][k4 * 4];
            const float4 a1 = *(const float4*)&As[2 * ty + 1][k4 * 4];
#pragma unroll
            for (int g = 0; g < 4; ++g) {
                const float4 w = *(const float4*)&Wsh[g][tx][k4 * 4];
                acc[0][g] += a0.x * w.x + a0.y * w.y + a0.z * w.z + a0.w * w.w;
                acc[1][g] += a1.x * w.x + a1.y * w.y + a1.z * w.z + a1.w * w.w;
            }
        }
        __syncthreads();
    }

    /* gate nonlinearities + state update (PyTorch order i,f,g,o) */
    const int j = j0 + tx;
#pragma unroll
    for (int i = 0; i < 2; ++i) {
        const int b = b0 + 2 * ty + i;
        const float gi = acc[i][0] + bias[0 * HID + j];
        const float gf = acc[i][1] + bias[1 * HID + j];
        const float gg = acc[i][2] + bias[2 * HID + j];
        const float go = acc[i][3] + bias[3 * HID + j];
        const float si = 1.0f / (1.0f + expf(-gi));
        const float sf = 1.0f / (1.0f + expf(-gf));
        const float so = 1.0f / (1.0f + expf(-go));
        const float c_new = sf * cbuf[b * HID + j] + si * tanhf(gg);
        const float h = so * tanhf(c_new);
        cbuf[b * HID + j]  = c_new;
        h_new[b * HID + j] = h;
        hn[2 * ty + i][tx] = h;
    }
    __syncthreads();

    /* feats[t] += h_tile @ lin_w_slice^T  (32 batches x 10 tags) */
    for (int idx = tid; idx < 32 * TAGS; idx += 256) {
        const int bl = idx / TAGS, tg = idx % TAGS;
        float p = 0.0f;
#pragma unroll
        for (int jj = 0; jj < 16; ++jj)
            p += hn[bl][jj] * lin_w[tg * (2 * HID) + dir * HID + j0 + jj];
        atomicAdd(&feats[(t * BATCH + b0 + bl) * TAGS + tg], p);
    }
}

/* ---------------- CRF: forward algorithm + gold score ----------------
 * grid = 8 blocks x 320 threads; block handles 32 batches; thread = (b,tag).
 */
__launch_bounds__(320)
__global__ void crf_kernel(const float* __restrict__ feats,
                           const int* __restrict__ labels,
                           const float* __restrict__ trans,
                           float* __restrict__ nll)
{
    const int tid = threadIdx.x;
    const int bl = tid / TAGS;   /* 0..31 */
    const int tg = tid % TAGS;   /* 0..9  */
    const int b = blockIdx.x * 32 + bl;

    __shared__ float fv[32][TAGS];
    __shared__ float tr[TAGS][TAGS];
    __shared__ float fs[32];
    __shared__ float gp[32][TAGS];

    if (tid < TAGS * TAGS) tr[tid / TAGS][tid % TAGS] = trans[tid];
    fv[bl][tg] = (tg == START_TAG) ? 0.0f : NEG_INF;
    __syncthreads();

    for (int t = 0; t < T_LEN; ++t) {
        float v[TAGS];
#pragma unroll
        for (int p = 0; p < TAGS; ++p) v[p] = fv[bl][p] + tr[tg][p];
        float m = v[0];
#pragma unroll
        for (int p = 1; p < TAGS; ++p) m = fmaxf(m, v[p]);
        float ssum = 0.0f;
#pragma unroll
        for (int p = 0; p < TAGS; ++p) ssum += expf(v[p] - m);
        const float nv = m + logf(ssum) + feats[(t * BATCH + b) * TAGS + tg];
        __syncthreads();
        fv[bl][tg] = nv;
        __syncthreads();
    }

    /* forward_score = LSE(fv + trans[STOP,:]) */
    if (tg == 0) {
        float v[TAGS];
        float m = NEG_INF;
#pragma unroll
        for (int p = 0; p < TAGS; ++p) {
            v[p] = fv[bl][p] + tr[STOP_TAG][p];
            m = fmaxf(m, v[p]);
        }
        float ssum = 0.0f;
#pragma unroll
        for (int p = 0; p < TAGS; ++p) ssum += expf(v[p] - m);
        fs[bl] = m + logf(ssum);
    }

    /* gold score: strided-t partials per tag-thread */
    float gpart = 0.0f;
    for (int t = tg; t < T_LEN; t += TAGS) {
        const int lab  = labels[t * BATCH + b];
        const int prev = (t == 0) ? START_TAG : labels[(t - 1) * BATCH + b];
        gpart += feats[(t * BATCH + b) * TAGS + lab] + tr[lab][prev];
    }
    gp[bl][tg] = gpart;
    __syncthreads();

    if (tg == 0) {
        float g = 0.0f;
#pragma unroll
        for (int p = 0; p < TAGS; ++p) g += gp[bl][p];
        g += tr[STOP_TAG][labels[(T_LEN - 1) * BATCH + b]];
        nll[b] = fs[bl] - g;
    }
}

/* ---------------- final mean reduction ---------------- */
__global__ void reduce_kernel(const float* __restrict__ nll, float* __restrict__ out)
{
    __shared__ float sdata[BATCH];
    const int tid = threadIdx.x;
    sdata[tid] = nll[tid];
    __syncthreads();
    for (int s = BATCH / 2; s > 0; s >>= 1) {
        if (tid < s) sdata[tid] += sdata[tid + s];
        __syncthreads();
    }
    if (tid == 0) out[0] = sdata[0] / (float)BATCH;
}

extern "C" void kernel_launch(void* const* d_in, const int* in_sizes, int n_in,
                              void* d_out, int out_size, void* d_ws, size_t ws_size,
                              hipStream_t stream)
{
    const float* features = (const float*)d_in[0];
    const int*   labels   = (const int*)d_in[1];
    /* d_in[2] = lengths (all T_LEN, unused) */
    const float* w_ih_f = (const float*)d_in[3];
    const float* w_hh_f = (const float*)d_in[4];
    const float* b_f    = (const float*)d_in[5];
    const float* w_ih_b = (const float*)d_in[6];
    const float* w_hh_b = (const float*)d_in[7];
    const float* b_b    = (const float*)d_in[8];
    const float* lin_w  = (const float*)d_in[9];
    const float* lin_b  = (const float*)d_in[10];
    const float* trans  = (const float*)d_in[11];

    float* ws  = (float*)d_ws;
    float* out = (float*)d_out;

    init_kernel<<<2048, 256, 0, stream>>>(ws, lin_b);

    for (int s = 0; s < T_LEN; ++s)
        lstm_step<<<256, 256, 0, stream>>>(features, w_ih_f, w_hh_f, b_f,
                                           w_ih_b, w_hh_b, b_b, lin_w, ws, s);

    crf_kernel<<<8, 320, 0, stream>>>(ws + WS_FEATS, labels, trans, ws + WS_NLL);
    reduce_kernel<<<1, BATCH, 0, stream>>>(ws + WS_NLL, out);
}

// Round 2
// 24052.199 us; speedup vs baseline: 1.6223x; 1.6223x over previous
//
#include <hip/hip_runtime.h>
#include <math.h>

#define T_LEN 1024
#define BATCH 256
#define IN_DIM 66
#define HID 256
#define TAGS 10
#define NEG_INF -10000.0f
#define START_TAG 8
#define STOP_TAG 9

#define NKS 11            /* k-steps of 32: 352 = 256 h + 66 x + 30 pad */
#define ALD_STRIDE 360    /* shorts per a_lds row (2-way-conflict-free) */

/* ---- workspace layout ---- */
#define WS_FF 0                                   /* [T][B][TAGS] f32, fwd  */
#define WS_FB (WS_FF + T_LEN * BATCH * TAGS)      /* [T][B][TAGS] f32, bwd  */
#define WS_NLL (WS_FB + T_LEN * BATCH * TAGS)     /* [B] f32                */
#define WS_SHORTF (WS_NLL + 256)                  /* short region begins    */
#define WP_SHORTS (2 * 64 * NKS * 64 * 8)         /* 720896 shorts          */
#define LP_OFF WP_SHORTS

typedef __attribute__((ext_vector_type(8))) short short8;
typedef __attribute__((ext_vector_type(4))) short short4v;
typedef __attribute__((ext_vector_type(4))) float float4v;

static __device__ __forceinline__ short f2bf(float x) {
    union { float f; unsigned u; } v; v.f = x;
    unsigned r = v.u + 0x7fff + ((v.u >> 16) & 1);   /* RNE */
    return (short)(r >> 16);
}

/* ---- prep: W -> MFMA A-fragment-linear bf16 layout ----
 * Wprep[dir][rt 0..63][ks 0..10][lane 0..63][8]:
 *   row = rt*16 + (lane&15); k = ks*32 + (lane>>4)*8 + j
 *   k<256 -> w_hh[row][k]; 256<=k<322 -> w_ih[row][k-256]; else 0 */
__global__ void prep_w(const float* __restrict__ wihf, const float* __restrict__ whhf,
                       const float* __restrict__ wihb, const float* __restrict__ whhb,
                       short* __restrict__ wp)
{
    const int tid = blockIdx.x * blockDim.x + threadIdx.x;
    if (tid >= 2 * 64 * NKS * 64) return;
    const int lane = tid & 63;
    const int rest = tid >> 6;
    const int ks = rest % NKS;
    const int rt = (rest / NKS) & 63;
    const int dir = rest / (NKS * 64);
    const float* whh = dir ? whhb : whhf;
    const float* wih = dir ? wihb : wihf;
    const int row = rt * 16 + (lane & 15);
    const int kb = ks * 32 + ((lane >> 4) << 3);
    short8 o;
#pragma unroll
    for (int j = 0; j < 8; ++j) {
        const int k = kb + j;
        float v = 0.0f;
        if (k < HID)               v = whh[row * HID + k];
        else if (k < HID + IN_DIM) v = wih[row * IN_DIM + (k - HID)];
        o[j] = f2bf(v);
    }
    *(short8*)&wp[(size_t)tid * 8] = o;
}

/* Lprep[dir][ks 0..7][lane][8]: tag = lane&15 (>=10 -> 0), k = ks*32+(lane>>4)*8+j */
__global__ void prep_l(const float* __restrict__ lin_w, short* __restrict__ lp)
{
    const int tid = blockIdx.x * blockDim.x + threadIdx.x;
    if (tid >= 2 * 8 * 64) return;
    const int lane = tid & 63;
    const int ks = (tid >> 6) & 7;
    const int dir = tid >> 9;
    const int tag = lane & 15;
    const int kb = ks * 32 + ((lane >> 4) << 3);
    short8 o;
#pragma unroll
    for (int j = 0; j < 8; ++j) {
        const int k = kb + j;
        const float v = (tag < TAGS) ? lin_w[tag * (2 * HID) + dir * HID + k] : 0.0f;
        o[j] = f2bf(v);
    }
    *(short8*)&lp[(size_t)tid * 8] = o;
}

/* ---- persistent BiLSTM: 16 blocks = 2 dirs x 8 batch-tiles(32), 512 thr ----
 * Wave w owns hidden slice [w*32, w*32+32) for all 4 gates.
 * MFMA: A = W rows (m = gate-row), B = h/x (n = batch), C row=(l>>4)*4+r, col=l&15.
 * c lives in registers across all 1024 steps; h ping-pongs through LDS. */
__launch_bounds__(512)
__global__ void bilstm_pers(const float* __restrict__ feat,
                            const float* __restrict__ b_f,
                            const float* __restrict__ b_b,
                            const short* __restrict__ wp_all,
                            const short* __restrict__ lp_all,
                            float* __restrict__ ff,
                            float* __restrict__ fb)
{
    const int dir = blockIdx.x & 1;
    const int b0 = (blockIdx.x >> 1) * 32;
    const int tid = threadIdx.x;
    const int lane = tid & 63;
    const int wv = tid >> 6;       /* wave 0..7 */
    const int l15 = lane & 15;
    const int lk = lane >> 4;      /* 0..3 */

    const float* bias = dir ? b_b : b_f;
    float* fout = dir ? fb : ff;
    const short8* wp = (const short8*)(wp_all + (size_t)dir * (64 * NKS * 64 * 8));
    const short8* lp = (const short8*)(lp_all + (size_t)dir * (8 * 64 * 8));

    __shared__ short a_lds[32 * ALD_STRIDE];

    for (int i = tid; i < 32 * ALD_STRIDE; i += 512) a_lds[i] = 0;
    __syncthreads();
    {   /* stage x for s=0 */
        const int t0 = dir ? (T_LEN - 1) : 0;
        for (int idx = tid; idx < 32 * IN_DIM; idx += 512) {
            const int b = idx / IN_DIM, kk = idx - b * IN_DIM;
            a_lds[b * ALD_STRIDE + HID + kk] =
                f2bf(feat[((size_t)t0 * BATCH + b0 + b) * IN_DIM + kk]);
        }
    }

    /* per-lane biases: j = wv*32 + u*16 + lk*4 + r */
    float bv[4][8];
#pragma unroll
    for (int g = 0; g < 4; ++g)
#pragma unroll
        for (int u = 0; u < 2; ++u)
#pragma unroll
            for (int r = 0; r < 4; ++r)
                bv[g][u * 4 + r] = bias[g * HID + wv * 32 + u * 16 + lk * 4 + r];

    float cst[2][2][4];
#pragma unroll
    for (int bt = 0; bt < 2; ++bt)
#pragma unroll
        for (int u = 0; u < 2; ++u)
#pragma unroll
            for (int r = 0; r < 4; ++r) cst[bt][u][r] = 0.0f;

    __syncthreads();

    for (int s = 0; s < T_LEN; ++s) {
        float4v acc[2][4][2];
#pragma unroll
        for (int bt = 0; bt < 2; ++bt)
#pragma unroll
            for (int g = 0; g < 4; ++g)
#pragma unroll
                for (int u = 0; u < 2; ++u)
                    acc[bt][g][u] = (float4v){0.f, 0.f, 0.f, 0.f};

        /* double-buffered k-loop: 11 ksteps x (8 W-frag loads + 2 A-frag ds_reads + 16 MFMA) */
        short8 wf[2][8], af[2][2];
#pragma unroll
        for (int g = 0; g < 4; ++g)
#pragma unroll
            for (int u = 0; u < 2; ++u)
                wf[0][g * 2 + u] = wp[((g * 16 + wv * 2 + u) * NKS + 0) * 64 + lane];
        af[0][0] = *(const short8*)&a_lds[l15 * ALD_STRIDE + lk * 8];
        af[0][1] = *(const short8*)&a_lds[(16 + l15) * ALD_STRIDE + lk * 8];

#pragma unroll
        for (int ks = 0; ks < NKS; ++ks) {
            const int cur = ks & 1, nxt = cur ^ 1;
            if (ks < NKS - 1) {
#pragma unroll
                for (int g = 0; g < 4; ++g)
#pragma unroll
                    for (int u = 0; u < 2; ++u)
                        wf[nxt][g * 2 + u] =
                            wp[((g * 16 + wv * 2 + u) * NKS + ks + 1) * 64 + lane];
                af[nxt][0] = *(const short8*)&a_lds[l15 * ALD_STRIDE + (ks + 1) * 32 + lk * 8];
                af[nxt][1] = *(const short8*)&a_lds[(16 + l15) * ALD_STRIDE + (ks + 1) * 32 + lk * 8];
            }
#pragma unroll
            for (int bt = 0; bt < 2; ++bt)
#pragma unroll
                for (int g = 0; g < 4; ++g)
#pragma unroll
                    for (int u = 0; u < 2; ++u)
                        acc[bt][g][u] = __builtin_amdgcn_mfma_f32_16x16x32_bf16(
                            wf[cur][g * 2 + u], af[cur][bt], acc[bt][g][u], 0, 0, 0);
        }

        /* fused tag projection of PREVIOUS h (still in a_lds); waves 0,1 */
        if (wv < 2 && s > 0) {
            const int tprev = dir ? (T_LEN - s) : (s - 1);
            float4v facc = {0.f, 0.f, 0.f, 0.f};
#pragma unroll
            for (int ks = 0; ks < 8; ++ks) {
                const short8 lf = lp[ks * 64 + lane];
                const short8 bfr =
                    *(const short8*)&a_lds[(wv * 16 + l15) * ALD_STRIDE + ks * 32 + lk * 8];
                facc = __builtin_amdgcn_mfma_f32_16x16x32_bf16(lf, bfr, facc, 0, 0, 0);
            }
#pragma unroll
            for (int r = 0; r < 4; ++r) {
                const int tag = lk * 4 + r;
                if (tag < TAGS)
                    fout[((size_t)tprev * BATCH + b0 + wv * 16 + l15) * TAGS + tag] = facc[r];
            }
        }

        /* epilogue: gates -> c,h (PyTorch order i,f,g,o) */
        float hq[2][2][4];
#pragma unroll
        for (int bt = 0; bt < 2; ++bt)
#pragma unroll
            for (int u = 0; u < 2; ++u)
#pragma unroll
                for (int r = 0; r < 4; ++r) {
                    const float gi = acc[bt][0][u][r] + bv[0][u * 4 + r];
                    const float gf = acc[bt][1][u][r] + bv[1][u * 4 + r];
                    const float gg = acc[bt][2][u][r] + bv[2][u * 4 + r];
                    const float go = acc[bt][3][u][r] + bv[3][u * 4 + r];
                    const float si = 1.0f / (1.0f + exp2f(gi * -1.44269504f));
                    const float sf = 1.0f / (1.0f + exp2f(gf * -1.44269504f));
                    const float so = 1.0f / (1.0f + exp2f(go * -1.44269504f));
                    const float tg = 2.0f / (1.0f + exp2f(gg * -2.88539008f)) - 1.0f;
                    const float cn = sf * cst[bt][u][r] + si * tg;
                    const float th = 2.0f / (1.0f + exp2f(cn * -2.88539008f)) - 1.0f;
                    cst[bt][u][r] = cn;
                    hq[bt][u][r] = so * th;
                }

        __syncthreads();   /* all reads of a_lds done */

        /* write new h (bf16, 8B packed) + stage x for next step */
#pragma unroll
        for (int bt = 0; bt < 2; ++bt)
#pragma unroll
            for (int u = 0; u < 2; ++u) {
                short4v pk;
#pragma unroll
                for (int r = 0; r < 4; ++r) pk[r] = f2bf(hq[bt][u][r]);
                const int row = bt * 16 + l15;
                const int j0 = wv * 32 + u * 16 + lk * 4;
                *(short4v*)&a_lds[row * ALD_STRIDE + j0] = pk;
            }
        if (s < T_LEN - 1) {
            const int tn = dir ? (T_LEN - 2 - s) : (s + 1);
            for (int idx = tid; idx < 32 * IN_DIM; idx += 512) {
                const int b = idx / IN_DIM, kk = idx - b * IN_DIM;
                a_lds[b * ALD_STRIDE + HID + kk] =
                    f2bf(feat[((size_t)tn * BATCH + b0 + b) * IN_DIM + kk]);
            }
        }
        __syncthreads();
    }

    /* final tag projection for the last h */
    if (wv < 2) {
        const int tlast = dir ? 0 : (T_LEN - 1);
        float4v facc = {0.f, 0.f, 0.f, 0.f};
#pragma unroll
        for (int ks = 0; ks < 8; ++ks) {
            const short8 lf = lp[ks * 64 + lane];
            const short8 bfr =
                *(const short8*)&a_lds[(wv * 16 + l15) * ALD_STRIDE + ks * 32 + lk * 8];
            facc = __builtin_amdgcn_mfma_f32_16x16x32_bf16(lf, bfr, facc, 0, 0, 0);
        }
#pragma unroll
        for (int r = 0; r < 4; ++r) {
            const int tag = lk * 4 + r;
            if (tag < TAGS)
                fout[((size_t)tlast * BATCH + b0 + wv * 16 + l15) * TAGS + tag] = facc[r];
        }
    }
}

/* ---- CRF forward + gold (feats = ff + fb + lin_b on read) ---- */
__launch_bounds__(320)
__global__ void crf_kernel(const float* __restrict__ ff, const float* __restrict__ fb,
                           const int* __restrict__ labels, const float* __restrict__ lin_b,
                           const float* __restrict__ trans, float* __restrict__ nll)
{
    const int tid = threadIdx.x;
    const int bl = tid / TAGS;
    const int tg = tid % TAGS;
    const int b = blockIdx.x * 32 + bl;

    __shared__ float fv[32][TAGS];
    __shared__ float tr[TAGS][TAGS];
    __shared__ float lb[TAGS];
    __shared__ float fs[32];
    __shared__ float gp[32][TAGS];

    if (tid < TAGS * TAGS) tr[tid / TAGS][tid % TAGS] = trans[tid];
    if (tid < TAGS) lb[tid] = lin_b[tid];
    fv[bl][tg] = (tg == START_TAG) ? 0.0f : NEG_INF;
    __syncthreads();

    const float myb = lb[tg];
    for (int t = 0; t < T_LEN; ++t) {
        float v[TAGS];
#pragma unroll
        for (int p = 0; p < TAGS; ++p) v[p] = fv[bl][p] + tr[tg][p];
        float m = v[0];
#pragma unroll
        for (int p = 1; p < TAGS; ++p) m = fmaxf(m, v[p]);
        float ssum = 0.0f;
#pragma unroll
        for (int p = 0; p < TAGS; ++p) ssum += expf(v[p] - m);
        const size_t base = ((size_t)t * BATCH + b) * TAGS;
        const float nv = m + logf(ssum) + ff[base + tg] + fb[base + tg] + myb;
        __syncthreads();
        fv[bl][tg] = nv;
        __syncthreads();
    }

    if (tg == 0) {
        float m = NEG_INF;
        float v[TAGS];
#pragma unroll
        for (int p = 0; p < TAGS; ++p) {
            v[p] = fv[bl][p] + tr[STOP_TAG][p];
            m = fmaxf(m, v[p]);
        }
        float ssum = 0.0f;
#pragma unroll
        for (int p = 0; p < TAGS; ++p) ssum += expf(v[p] - m);
        fs[bl] = m + logf(ssum);
    }

    float gpart = 0.0f;
    for (int t = tg; t < T_LEN; t += TAGS) {
        const int lab = labels[t * BATCH + b];
        const int prev = (t == 0) ? START_TAG : labels[(t - 1) * BATCH + b];
        const size_t base = ((size_t)t * BATCH + b) * TAGS;
        gpart += ff[base + lab] + fb[base + lab] + lb[lab] + tr[lab][prev];
    }
    gp[bl][tg] = gpart;
    __syncthreads();

    if (tg == 0) {
        float g = 0.0f;
#pragma unroll
        for (int p = 0; p < TAGS; ++p) g += gp[bl][p];
        g += tr[STOP_TAG][labels[(T_LEN - 1) * BATCH + b]];
        nll[b] = fs[bl] - g;
    }
}

__global__ void reduce_kernel(const float* __restrict__ nll, float* __restrict__ out)
{
    __shared__ float sdata[BATCH];
    const int tid = threadIdx.x;
    sdata[tid] = nll[tid];
    __syncthreads();
    for (int s = BATCH / 2; s > 0; s >>= 1) {
        if (tid < s) sdata[tid] += sdata[tid + s];
        __syncthreads();
    }
    if (tid == 0) out[0] = sdata[0] / (float)BATCH;
}

extern "C" void kernel_launch(void* const* d_in, const int* in_sizes, int n_in,
                              void* d_out, int out_size, void* d_ws, size_t ws_size,
                              hipStream_t stream)
{
    const float* features = (const float*)d_in[0];
    const int*   labels   = (const int*)d_in[1];
    const float* w_ih_f = (const float*)d_in[3];
    const float* w_hh_f = (const float*)d_in[4];
    const float* b_f    = (const float*)d_in[5];
    const float* w_ih_b = (const float*)d_in[6];
    const float* w_hh_b = (const float*)d_in[7];
    const float* b_b    = (const float*)d_in[8];
    const float* lin_w  = (const float*)d_in[9];
    const float* lin_b  = (const float*)d_in[10];
    const float* trans  = (const float*)d_in[11];

    float* ws = (float*)d_ws;
    short* wsS = (short*)(ws + WS_SHORTF);
    float* out = (float*)d_out;

    prep_w<<<(2 * 64 * NKS * 64) / 256, 256, 0, stream>>>(w_ih_f, w_hh_f, w_ih_b, w_hh_b, wsS);
    prep_l<<<4, 256, 0, stream>>>(lin_w, wsS + LP_OFF);

    bilstm_pers<<<16, 512, 0, stream>>>(features, b_f, b_b, wsS, wsS + LP_OFF,
                                        ws + WS_FF, ws + WS_FB);

    crf_kernel<<<8, 320, 0, stream>>>(ws + WS_FF, ws + WS_FB, labels, lin_b, trans, ws + WS_NLL);
    reduce_kernel<<<1, BATCH, 0, stream>>>(ws + WS_NLL, out);
}

// Round 3
// 18883.815 us; speedup vs baseline: 2.0663x; 1.2737x over previous
//
#include <hip/hip_runtime.h>
#include <math.h>

#define T_LEN 1024
#define BATCH 256
#define IN_DIM 66
#define HID 256
#define TAGS 10
#define NEG_INF -10000.0f
#define START_TAG 8
#define STOP_TAG 9

#define NKS 11            /* k-steps of 32: 352 = 256 h + 66 x + 30 pad */
#define ALD_STRIDE 360    /* shorts per a_lds row */

/* ---- workspace layout ---- */
#define WS_FF 0                                   /* [T][B][TAGS] f32, fwd  */
#define WS_FB (WS_FF + T_LEN * BATCH * TAGS)      /* [T][B][TAGS] f32, bwd  */
#define WS_NLL (WS_FB + T_LEN * BATCH * TAGS)     /* [B] f32                */
#define WS_SHORTF (WS_NLL + 256)                  /* short region begins    */
#define WP_SHORTS (2 * 64 * NKS * 64 * 8)         /* 720896 shorts          */
#define LP_OFF WP_SHORTS

typedef __attribute__((ext_vector_type(8))) short short8;
typedef __attribute__((ext_vector_type(4))) short short4v;
typedef __attribute__((ext_vector_type(4))) float float4v;

static __device__ __forceinline__ short f2bf(float x) {
    union { float f; unsigned u; } v; v.f = x;
    unsigned r = v.u + 0x7fff + ((v.u >> 16) & 1);   /* RNE */
    return (short)(r >> 16);
}

/* ---- prep: W -> MFMA A-fragment-linear bf16 layout ----
 * Wprep[dir][rt 0..63][ks 0..10][lane 0..63][8]:
 *   row = rt*16 + (lane&15); k = ks*32 + (lane>>4)*8 + j
 *   k<256 -> w_hh[row][k]; 256<=k<322 -> w_ih[row][k-256]; else 0 */
__global__ void prep_w(const float* __restrict__ wihf, const float* __restrict__ whhf,
                       const float* __restrict__ wihb, const float* __restrict__ whhb,
                       short* __restrict__ wp)
{
    const int tid = blockIdx.x * blockDim.x + threadIdx.x;
    if (tid >= 2 * 64 * NKS * 64) return;
    const int lane = tid & 63;
    const int rest = tid >> 6;
    const int ks = rest % NKS;
    const int rt = (rest / NKS) & 63;
    const int dir = rest / (NKS * 64);
    const float* whh = dir ? whhb : whhf;
    const float* wih = dir ? wihb : wihf;
    const int row = rt * 16 + (lane & 15);
    const int kb = ks * 32 + ((lane >> 4) << 3);
    short8 o;
#pragma unroll
    for (int j = 0; j < 8; ++j) {
        const int k = kb + j;
        float v = 0.0f;
        if (k < HID)               v = whh[row * HID + k];
        else if (k < HID + IN_DIM) v = wih[row * IN_DIM + (k - HID)];
        o[j] = f2bf(v);
    }
    *(short8*)&wp[(size_t)tid * 8] = o;
}

/* Lprep[dir][ks 0..7][lane][8]: tag = lane&15 (>=10 -> 0), k = ks*32+(lane>>4)*8+j */
__global__ void prep_l(const float* __restrict__ lin_w, short* __restrict__ lp)
{
    const int tid = blockIdx.x * blockDim.x + threadIdx.x;
    if (tid >= 2 * 8 * 64) return;
    const int lane = tid & 63;
    const int ks = (tid >> 6) & 7;
    const int dir = tid >> 9;
    const int tag = lane & 15;
    const int kb = ks * 32 + ((lane >> 4) << 3);
    short8 o;
#pragma unroll
    for (int j = 0; j < 8; ++j) {
        const int k = kb + j;
        const float v = (tag < TAGS) ? lin_w[tag * (2 * HID) + dir * HID + k] : 0.0f;
        o[j] = f2bf(v);
    }
    *(short8*)&lp[(size_t)tid * 8] = o;
}

/* ---- persistent BiLSTM: 32 blocks = 2 dirs x 16 batch-tiles(16), 512 thr ----
 * Wave w owns hidden slice [w*32, w*32+32) for all 4 gates; 16 batches/block.
 * MFMA: A = W rows (m = gate-row), B = h/x (n = batch), C row=(l>>4)*4+r, col=l&15.
 * c lives in registers across all 1024 steps; h ping-pongs through LDS.
 * __launch_bounds__(512,2): 2 waves/EU -> 256-VGPR budget (round-2 spilled at 128). */
__launch_bounds__(512, 2)
__global__ void bilstm_pers(const float* __restrict__ feat,
                            const float* __restrict__ b_f,
                            const float* __restrict__ b_b,
                            const short* __restrict__ wp_all,
                            const short* __restrict__ lp_all,
                            float* __restrict__ ff,
                            float* __restrict__ fb)
{
    const int dir = blockIdx.x & 1;
    const int b0 = (blockIdx.x >> 1) * 16;
    const int tid = threadIdx.x;
    const int lane = tid & 63;
    const int wv = tid >> 6;       /* wave 0..7 */
    const int l15 = lane & 15;
    const int lk = lane >> 4;      /* 0..3 */

    const float* bias = dir ? b_b : b_f;
    float* fout = dir ? fb : ff;
    const short8* wp = (const short8*)(wp_all + (size_t)dir * (64 * NKS * 64 * 8));
    const short8* lp = (const short8*)(lp_all + (size_t)dir * (8 * 64 * 8));

    __shared__ short a_lds[16 * ALD_STRIDE];

    for (int i = tid; i < 16 * ALD_STRIDE; i += 512) a_lds[i] = 0;
    __syncthreads();
    {   /* stage x for s=0 */
        const int t0 = dir ? (T_LEN - 1) : 0;
        for (int idx = tid; idx < 16 * IN_DIM; idx += 512) {
            const int b = idx / IN_DIM, kk = idx - b * IN_DIM;
            a_lds[b * ALD_STRIDE + HID + kk] =
                f2bf(feat[((size_t)t0 * BATCH + b0 + b) * IN_DIM + kk]);
        }
    }

    /* per-lane biases: j = wv*32 + u*16 + lk*4 + r */
    float bv[4][8];
#pragma unroll
    for (int g = 0; g < 4; ++g)
#pragma unroll
        for (int u = 0; u < 2; ++u)
#pragma unroll
            for (int r = 0; r < 4; ++r)
                bv[g][u * 4 + r] = bias[g * HID + wv * 32 + u * 16 + lk * 4 + r];

    float cst[2][4];
#pragma unroll
    for (int u = 0; u < 2; ++u)
#pragma unroll
        for (int r = 0; r < 4; ++r) cst[u][r] = 0.0f;

    __syncthreads();

    for (int s = 0; s < T_LEN; ++s) {
        float4v acc[4][2];
#pragma unroll
        for (int g = 0; g < 4; ++g)
#pragma unroll
            for (int u = 0; u < 2; ++u)
                acc[g][u] = (float4v){0.f, 0.f, 0.f, 0.f};

        /* k-loop: 11 ksteps x (8 W-frag loads prefetched 2 deep + 1 A ds_read + 8 MFMA) */
        short8 wf[3][8], af[2];
#pragma unroll
        for (int p = 0; p < 2; ++p)
#pragma unroll
            for (int g = 0; g < 4; ++g)
#pragma unroll
                for (int u = 0; u < 2; ++u)
                    wf[p][g * 2 + u] = wp[((g * 16 + wv * 2 + u) * NKS + p) * 64 + lane];
        af[0] = *(const short8*)&a_lds[l15 * ALD_STRIDE + lk * 8];

#pragma unroll
        for (int ks = 0; ks < NKS; ++ks) {
            const int cur = ks % 3;
            if (ks + 2 < NKS) {
                const int pre = (ks + 2) % 3;
#pragma unroll
                for (int g = 0; g < 4; ++g)
#pragma unroll
                    for (int u = 0; u < 2; ++u)
                        wf[pre][g * 2 + u] =
                            wp[((g * 16 + wv * 2 + u) * NKS + ks + 2) * 64 + lane];
            }
            if (ks + 1 < NKS)
                af[(ks + 1) & 1] =
                    *(const short8*)&a_lds[l15 * ALD_STRIDE + (ks + 1) * 32 + lk * 8];
#pragma unroll
            for (int g = 0; g < 4; ++g)
#pragma unroll
                for (int u = 0; u < 2; ++u)
                    acc[g][u] = __builtin_amdgcn_mfma_f32_16x16x32_bf16(
                        wf[cur][g * 2 + u], af[ks & 1], acc[g][u], 0, 0, 0);
        }

        /* fused tag projection of PREVIOUS h (still in a_lds); wave 0 */
        if (wv == 0 && s > 0) {
            const int tprev = dir ? (T_LEN - s) : (s - 1);
            float4v facc = {0.f, 0.f, 0.f, 0.f};
#pragma unroll
            for (int ks = 0; ks < 8; ++ks) {
                const short8 lf = lp[ks * 64 + lane];
                const short8 bfr =
                    *(const short8*)&a_lds[l15 * ALD_STRIDE + ks * 32 + lk * 8];
                facc = __builtin_amdgcn_mfma_f32_16x16x32_bf16(lf, bfr, facc, 0, 0, 0);
            }
#pragma unroll
            for (int r = 0; r < 4; ++r) {
                const int tag = lk * 4 + r;
                if (tag < TAGS)
                    fout[((size_t)tprev * BATCH + b0 + l15) * TAGS + tag] = facc[r];
            }
        }

        /* epilogue: gates -> c,h (PyTorch order i,f,g,o); batch = l15 per lane */
        float hq[2][4];
#pragma unroll
        for (int u = 0; u < 2; ++u)
#pragma unroll
            for (int r = 0; r < 4; ++r) {
                const float gi = acc[0][u][r] + bv[0][u * 4 + r];
                const float gf = acc[1][u][r] + bv[1][u * 4 + r];
                const float gg = acc[2][u][r] + bv[2][u * 4 + r];
                const float go = acc[3][u][r] + bv[3][u * 4 + r];
                const float si = 1.0f / (1.0f + exp2f(gi * -1.44269504f));
                const float sf = 1.0f / (1.0f + exp2f(gf * -1.44269504f));
                const float so = 1.0f / (1.0f + exp2f(go * -1.44269504f));
                const float tg = 2.0f / (1.0f + exp2f(gg * -2.88539008f)) - 1.0f;
                const float cn = sf * cst[u][r] + si * tg;
                const float th = 2.0f / (1.0f + exp2f(cn * -2.88539008f)) - 1.0f;
                cst[u][r] = cn;
                hq[u][r] = so * th;
            }

        __syncthreads();   /* all reads of a_lds done */

        /* write new h (bf16, 8B packed) + stage x for next step */
#pragma unroll
        for (int u = 0; u < 2; ++u) {
            short4v pk;
#pragma unroll
            for (int r = 0; r < 4; ++r) pk[r] = f2bf(hq[u][r]);
            *(short4v*)&a_lds[l15 * ALD_STRIDE + wv * 32 + u * 16 + lk * 4] = pk;
        }
        if (s < T_LEN - 1) {
            const int tn = dir ? (T_LEN - 2 - s) : (s + 1);
            for (int idx = tid; idx < 16 * IN_DIM; idx += 512) {
                const int b = idx / IN_DIM, kk = idx - b * IN_DIM;
                a_lds[b * ALD_STRIDE + HID + kk] =
                    f2bf(feat[((size_t)tn * BATCH + b0 + b) * IN_DIM + kk]);
            }
        }
        __syncthreads();
    }

    /* final tag projection for the last h */
    if (wv == 0) {
        const int tlast = dir ? 0 : (T_LEN - 1);
        float4v facc = {0.f, 0.f, 0.f, 0.f};
#pragma unroll
        for (int ks = 0; ks < 8; ++ks) {
            const short8 lf = lp[ks * 64 + lane];
            const short8 bfr =
                *(const short8*)&a_lds[l15 * ALD_STRIDE + ks * 32 + lk * 8];
            facc = __builtin_amdgcn_mfma_f32_16x16x32_bf16(lf, bfr, facc, 0, 0, 0);
        }
#pragma unroll
        for (int r = 0; r < 4; ++r) {
            const int tag = lk * 4 + r;
            if (tag < TAGS)
                fout[((size_t)tlast * BATCH + b0 + l15) * TAGS + tag] = facc[r];
        }
    }
}

/* ---- CRF forward + gold (feats = ff + fb + lin_b on read) ---- */
__launch_bounds__(320)
__global__ void crf_kernel(const float* __restrict__ ff, const float* __restrict__ fb,
                           const int* __restrict__ labels, const float* __restrict__ lin_b,
                           const float* __restrict__ trans, float* __restrict__ nll)
{
    const int tid = threadIdx.x;
    const int bl = tid / TAGS;
    const int tg = tid % TAGS;
    const int b = blockIdx.x * 32 + bl;

    __shared__ float fv[32][TAGS];
    __shared__ float tr[TAGS][TAGS];
    __shared__ float lb[TAGS];
    __shared__ float fs[32];
    __shared__ float gp[32][TAGS];

    if (tid < TAGS * TAGS) tr[tid / TAGS][tid % TAGS] = trans[tid];
    if (tid < TAGS) lb[tid] = lin_b[tid];
    fv[bl][tg] = (tg == START_TAG) ? 0.0f : NEG_INF;
    __syncthreads();

    const float myb = lb[tg];
    for (int t = 0; t < T_LEN; ++t) {
        float v[TAGS];
#pragma unroll
        for (int p = 0; p < TAGS; ++p) v[p] = fv[bl][p] + tr[tg][p];
        float m = v[0];
#pragma unroll
        for (int p = 1; p < TAGS; ++p) m = fmaxf(m, v[p]);
        float ssum = 0.0f;
#pragma unroll
        for (int p = 0; p < TAGS; ++p) ssum += expf(v[p] - m);
        const size_t base = ((size_t)t * BATCH + b) * TAGS;
        const float nv = m + logf(ssum) + ff[base + tg] + fb[base + tg] + myb;
        __syncthreads();
        fv[bl][tg] = nv;
        __syncthreads();
    }

    if (tg == 0) {
        float m = NEG_INF;
        float v[TAGS];
#pragma unroll
        for (int p = 0; p < TAGS; ++p) {
            v[p] = fv[bl][p] + tr[STOP_TAG][p];
            m = fmaxf(m, v[p]);
        }
        float ssum = 0.0f;
#pragma unroll
        for (int p = 0; p < TAGS; ++p) ssum += expf(v[p] - m);
        fs[bl] = m + logf(ssum);
    }

    float gpart = 0.0f;
    for (int t = tg; t < T_LEN; t += TAGS) {
        const int lab = labels[t * BATCH + b];
        const int prev = (t == 0) ? START_TAG : labels[(t - 1) * BATCH + b];
        const size_t base = ((size_t)t * BATCH + b) * TAGS;
        gpart += ff[base + lab] + fb[base + lab] + lb[lab] + tr[lab][prev];
    }
    gp[bl][tg] = gpart;
    __syncthreads();

    if (tg == 0) {
        float g = 0.0f;
#pragma unroll
        for (int p = 0; p < TAGS; ++p) g += gp[bl][p];
        g += tr[STOP_TAG][labels[(T_LEN - 1) * BATCH + b]];
        nll[b] = fs[bl] - g;
    }
}

__global__ void reduce_kernel(const float* __restrict__ nll, float* __restrict__ out)
{
    __shared__ float sdata[BATCH];
    const int tid = threadIdx.x;
    sdata[tid] = nll[tid];
    __syncthreads();
    for (int s = BATCH / 2; s > 0; s >>= 1) {
        if (tid < s) sdata[tid] += sdata[tid + s];
        __syncthreads();
    }
    if (tid == 0) out[0] = sdata[0] / (float)BATCH;
}

extern "C" void kernel_launch(void* const* d_in, const int* in_sizes, int n_in,
                              void* d_out, int out_size, void* d_ws, size_t ws_size,
                              hipStream_t stream)
{
    const float* features = (const float*)d_in[0];
    const int*   labels   = (const int*)d_in[1];
    const float* w_ih_f = (const float*)d_in[3];
    const float* w_hh_f = (const float*)d_in[4];
    const float* b_f    = (const float*)d_in[5];
    const float* w_ih_b = (const float*)d_in[6];
    const float* w_hh_b = (const float*)d_in[7];
    const float* b_b    = (const float*)d_in[8];
    const float* lin_w  = (const float*)d_in[9];
    const float* lin_b  = (const float*)d_in[10];
    const float* trans  = (const float*)d_in[11];

    float* ws = (float*)d_ws;
    short* wsS = (short*)(ws + WS_SHORTF);
    float* out = (float*)d_out;

    prep_w<<<(2 * 64 * NKS * 64) / 256, 256, 0, stream>>>(w_ih_f, w_hh_f, w_ih_b, w_hh_b, wsS);
    prep_l<<<4, 256, 0, stream>>>(lin_w, wsS + LP_OFF);

    bilstm_pers<<<32, 512, 0, stream>>>(features, b_f, b_b, wsS, wsS + LP_OFF,
                                        ws + WS_FF, ws + WS_FB);

    crf_kernel<<<8, 320, 0, stream>>>(ws + WS_FF, ws + WS_FB, labels, lin_b, trans, ws + WS_NLL);
    reduce_kernel<<<1, BATCH, 0, stream>>>(ws + WS_NLL, out);
}

// Round 4
// 13694.757 us; speedup vs baseline: 2.8493x; 1.3789x over previous
//
#include <hip/hip_runtime.h>
#include <math.h>

#define T_LEN 1024
#define BATCH 256
#define IN_DIM 66
#define HID 256
#define TAGS 10
#define NEG_INF -10000.0f
#define START_TAG 8
#define STOP_TAG 9

/* ---- workspace layout ---- */
#define WS_FF 0                                   /* [T][B][TAGS] f32, fwd  */
#define WS_FB (WS_FF + T_LEN * BATCH * TAGS)      /* [T][B][TAGS] f32, bwd  */
#define WS_NLL (WS_FB + T_LEN * BATCH * TAGS)     /* [B] f32                */
#define WS_SHORTF (WS_NLL + 256)                  /* short region begins    */
#define LP_OFF (2 * 8 * 88 * 64 * 8)              /* after wp2: 720896      */
#define XP_OFF (LP_OFF + 2 * 8 * 64 * 8)          /* after lp: 729088       */

typedef __attribute__((ext_vector_type(8))) short short8;
typedef __attribute__((ext_vector_type(4))) short short4v;
typedef __attribute__((ext_vector_type(4))) float float4v;

static __device__ __forceinline__ short f2bf(float x) {
    union { float f; unsigned u; } v; v.f = x;
    unsigned r = v.u + 0x7fff + ((v.u >> 16) & 1);   /* RNE */
    return (short)(r >> 16);
}

/* ---- prep_w2: weights -> per-(dir,wave) class-ordered MFMA A-frag layout ----
 * wp2[dir][wv][cfi 0..87][lane][8], cfi = ks*8 + gu:
 *   gu = g*2+u; rt = g*16 + wv*2 + u; row = rt*16 + (lane&15)
 *   k = ks*32 + (lane>>4)*8 + j
 *   k<256 -> w_hh[row][k]; k<322 -> w_ih[row][k-256]; k==322 -> bias[row]; else 0
 * Classes: cfi 0..31 VGPR-resident, 32..47 LDS-resident, 48..87 streamed. */
__global__ void prep_w2(const float* __restrict__ wihf, const float* __restrict__ whhf,
                        const float* __restrict__ bf_,
                        const float* __restrict__ wihb, const float* __restrict__ whhb,
                        const float* __restrict__ bb_,
                        short* __restrict__ wp)
{
    const int tid = blockIdx.x * blockDim.x + threadIdx.x;
    if (tid >= 2 * 8 * 88 * 64) return;
    const int lane = tid & 63;
    int rest = tid >> 6;
    const int cfi = rest % 88; rest /= 88;
    const int wv = rest & 7;
    const int dir = rest >> 3;
    const int ks = cfi >> 3, gu = cfi & 7;
    const int g = gu >> 1, u = gu & 1;
    const int row = (g * 16 + wv * 2 + u) * 16 + (lane & 15);
    const int kb = ks * 32 + ((lane >> 4) << 3);
    const float* whh = dir ? whhb : whhf;
    const float* wih = dir ? wihb : wihf;
    const float* bia = dir ? bb_ : bf_;
    short8 o;
#pragma unroll
    for (int j = 0; j < 8; ++j) {
        const int k = kb + j;
        float v = 0.0f;
        if (k < HID)                    v = whh[row * HID + k];
        else if (k < HID + IN_DIM)      v = wih[row * IN_DIM + (k - HID)];
        else if (k == HID + IN_DIM)     v = bia[row];   /* bias baked at k=322 */
        o[j] = f2bf(v);
    }
    *(short8*)&wp[(size_t)tid * 8] = o;
}

/* lp[dir][ks 0..7][lane][8]: tag = lane&15 (>=10 -> 0), k = ks*32+(lane>>4)*8+j */
__global__ void prep_l(const float* __restrict__ lin_w, short* __restrict__ lp)
{
    const int tid = blockIdx.x * blockDim.x + threadIdx.x;
    if (tid >= 2 * 8 * 64) return;
    const int lane = tid & 63;
    const int ks = (tid >> 6) & 7;
    const int dir = tid >> 9;
    const int tag = lane & 15;
    const int kb = ks * 32 + ((lane >> 4) << 3);
    short8 o;
#pragma unroll
    for (int j = 0; j < 8; ++j) {
        const int k = kb + j;
        const float v = (tag < TAGS) ? lin_w[tag * (2 * HID) + dir * HID + k] : 0.0f;
        o[j] = f2bf(v);
    }
    *(short8*)&lp[(size_t)tid * 8] = o;
}

/* ---- prep_x: features -> bf16 B-frag rows xp[t*B+b][72]:
 * kk<66 = feat, kk==66 = 1.0 (multiplies the baked bias column), else 0 */
__global__ void prep_x(const float* __restrict__ feat, short* __restrict__ xp)
{
    const int tid = blockIdx.x * blockDim.x + threadIdx.x;
    if (tid >= T_LEN * BATCH * 9) return;
    const int k0 = (tid % 9) * 8;
    const int tb = tid / 9;
    const float* row = feat + (size_t)tb * IN_DIM;
    short8 o;
#pragma unroll
    for (int j = 0; j < 8; ++j) {
        const int kk = k0 + j;
        o[j] = (kk < IN_DIM) ? f2bf(row[kk]) : ((kk == IN_DIM) ? (short)0x3F80 : (short)0);
    }
    *(short8*)&xp[(size_t)tb * 72 + k0] = o;
}

/* ---- persistent BiLSTM: 32 blocks = 2 dirs x 16 batch-tiles(16), 512 thr ----
 * Wave wv owns hidden [wv*32, wv*32+32) x all 4 gates; c stays in registers.
 * Weight frags partitioned: 32 VGPR-resident + 16 LDS-resident + 40 L2-streamed
 * per wave per step (cuts the per-step L2 stream 720KB -> 320KB/block).
 * Bias baked into weights (k=322 column * constant-1 x input). */
#define LDA(ks) (*(const short8*)&a_lds[l15 * 256 + (ks) * 32 + lk * 8])
#define LW(li)  (*(const short8*)&wlds[(wv * 16 + (li)) * 512 + lane * 8])
#define SW(si)  (wp8[sbase + (si) * 64])
#define MF(gu, W, B) acc[(gu) >> 1][(gu) & 1] = \
    __builtin_amdgcn_mfma_f32_16x16x32_bf16((W), (B), acc[(gu) >> 1][(gu) & 1], 0, 0, 0)
#define MF8W(base, B) do { MF(0, wfr[(base) + 0], B); MF(1, wfr[(base) + 1], B); \
    MF(2, wfr[(base) + 2], B); MF(3, wfr[(base) + 3], B); MF(4, wfr[(base) + 4], B); \
    MF(5, wfr[(base) + 5], B); MF(6, wfr[(base) + 6], B); MF(7, wfr[(base) + 7], B); } while (0)

__launch_bounds__(512, 2)
__global__ void bilstm_pers(const short* __restrict__ wp2,
                            const short* __restrict__ xp,
                            const short* __restrict__ lp_all,
                            float* __restrict__ ff, float* __restrict__ fb)
{
    const int dir = blockIdx.x & 1;
    const int b0 = (blockIdx.x >> 1) * 16;
    const int tid = threadIdx.x;
    const int lane = tid & 63;
    const int wv = tid >> 6;       /* wave 0..7 */
    const int l15 = lane & 15;
    const int lk = lane >> 4;      /* 0..3 */

    float* fout = dir ? fb : ff;
    const short8* wp8 = (const short8*)wp2;
    const int fbase = (dir * 8 + wv) * 88;
    const short8* lp = (const short8*)lp_all + dir * 512;

    __shared__ short a_lds[16 * 256];      /* h tile: [batch 16][k 256] bf16 */
    __shared__ short wlds[8 * 16 * 512];   /* 128 KB LDS-resident weight frags */

    for (int i = tid; i < 16 * 256; i += 512) a_lds[i] = 0;

    /* one-time: VGPR-resident frags + LDS staging */
    short8 wfr[32];
#pragma unroll
    for (int c = 0; c < 32; ++c) wfr[c] = wp8[(fbase + c) * 64 + lane];
#pragma unroll
    for (int li = 0; li < 16; ++li) {
        short8 v = wp8[(fbase + 32 + li) * 64 + lane];
        *(short8*)&wlds[(wv * 16 + li) * 512 + lane * 8] = v;
    }
    const int sbase = (fbase + 48) * 64 + lane;

    float cst[2][4];
#pragma unroll
    for (int u = 0; u < 2; ++u)
#pragma unroll
        for (int r = 0; r < 4; ++r) cst[u][r] = 0.0f;

    __syncthreads();

#pragma unroll 1
    for (int s = 0; s < T_LEN; ++s) {
        const int t = dir ? (T_LEN - 1 - s) : s;

        /* x B-frags straight from prepped global (issued early, used at p8..10) */
        const short* xrow = xp + ((size_t)t * BATCH + b0 + l15) * 72;
        short8 xf0 = *(const short8*)&xrow[lk * 8];
        short8 xf1 = *(const short8*)&xrow[32 + lk * 8];
        short8 xf2 = {0, 0, 0, 0, 0, 0, 0, 0};
        if (lk == 0) xf2 = *(const short8*)&xrow[64];

        float4v acc[4][2];
#pragma unroll
        for (int g = 0; g < 4; ++g)
#pragma unroll
            for (int u = 0; u < 2; ++u)
                acc[g][u] = (float4v){0.f, 0.f, 0.f, 0.f};

        short8 af0 = LDA(0), af1 = LDA(1);
        /* p0..3: VGPR-resident weights, h ks 0..3 */
        MF8W(0, af0);  af0 = LDA(2);
        MF8W(8, af1);  af1 = LDA(3);
        MF8W(16, af0); af0 = LDA(4);
        MF8W(24, af1); af1 = LDA(5);
        /* p4..5: LDS-resident weights, h ks 4..5 */
        {
            short8 w0 = LW(0), w1 = LW(1), w2 = LW(2), w3 = LW(3),
                   w4 = LW(4), w5 = LW(5), w6 = LW(6), w7 = LW(7);
            MF(0, w0, af0); MF(1, w1, af0); MF(2, w2, af0); MF(3, w3, af0);
            MF(4, w4, af0); MF(5, w5, af0); MF(6, w6, af0); MF(7, w7, af0);
            af0 = LDA(6);
        }
        {
            short8 w0 = LW(8), w1 = LW(9), w2 = LW(10), w3 = LW(11),
                   w4 = LW(12), w5 = LW(13), w6 = LW(14), w7 = LW(15);
            MF(0, w0, af1); MF(1, w1, af1); MF(2, w2, af1); MF(3, w3, af1);
            MF(4, w4, af1); MF(5, w5, af1); MF(6, w6, af1); MF(7, w7, af1);
            af1 = LDA(7);
        }
        /* p6..7: streamed weights, h ks 6..7 */
        {
            short8 w0 = SW(0), w1 = SW(1), w2 = SW(2), w3 = SW(3),
                   w4 = SW(4), w5 = SW(5), w6 = SW(6), w7 = SW(7);
            MF(0, w0, af0); MF(1, w1, af0); MF(2, w2, af0); MF(3, w3, af0);
            MF(4, w4, af0); MF(5, w5, af0); MF(6, w6, af0); MF(7, w7, af0);
        }
        {
            short8 w0 = SW(8), w1 = SW(9), w2 = SW(10), w3 = SW(11),
                   w4 = SW(12), w5 = SW(13), w6 = SW(14), w7 = SW(15);
            MF(0, w0, af1); MF(1, w1, af1); MF(2, w2, af1); MF(3, w3, af1);
            MF(4, w4, af1); MF(5, w5, af1); MF(6, w6, af1); MF(7, w7, af1);
        }
        /* p8..10: streamed weights, x frags (incl. baked bias column) */
        {
            short8 w0 = SW(16), w1 = SW(17), w2 = SW(18), w3 = SW(19),
                   w4 = SW(20), w5 = SW(21), w6 = SW(22), w7 = SW(23);
            MF(0, w0, xf0); MF(1, w1, xf0); MF(2, w2, xf0); MF(3, w3, xf0);
            MF(4, w4, xf0); MF(5, w5, xf0); MF(6, w6, xf0); MF(7, w7, xf0);
        }
        {
            short8 w0 = SW(24), w1 = SW(25), w2 = SW(26), w3 = SW(27),
                   w4 = SW(28), w5 = SW(29), w6 = SW(30), w7 = SW(31);
            MF(0, w0, xf1); MF(1, w1, xf1); MF(2, w2, xf1); MF(3, w3, xf1);
            MF(4, w4, xf1); MF(5, w5, xf1); MF(6, w6, xf1); MF(7, w7, xf1);
        }
        {
            short8 w0 = SW(32), w1 = SW(33), w2 = SW(34), w3 = SW(35),
                   w4 = SW(36), w5 = SW(37), w6 = SW(38), w7 = SW(39);
            MF(0, w0, xf2); MF(1, w1, xf2); MF(2, w2, xf2); MF(3, w3, xf2);
            MF(4, w4, xf2); MF(5, w5, xf2); MF(6, w6, xf2); MF(7, w7, xf2);
        }

        /* fused tag projection of PREVIOUS h (still in a_lds); wave 0 */
        if (wv == 0 && s > 0) {
            const int tprev = dir ? (T_LEN - s) : (s - 1);
            float4v facc = {0.f, 0.f, 0.f, 0.f};
#pragma unroll
            for (int ks = 0; ks < 8; ++ks) {
                const short8 lf = lp[ks * 64 + lane];
                const short8 bfr = LDA(ks);
                facc = __builtin_amdgcn_mfma_f32_16x16x32_bf16(lf, bfr, facc, 0, 0, 0);
            }
#pragma unroll
            for (int r = 0; r < 4; ++r) {
                const int tag = lk * 4 + r;
                if (tag < TAGS)
                    fout[((size_t)tprev * BATCH + b0 + l15) * TAGS + tag] = facc[r];
            }
        }

        /* epilogue: gates -> c,h (i,f,g,o); bias already in acc via baked column */
        float hq[2][4];
#pragma unroll
        for (int u = 0; u < 2; ++u)
#pragma unroll
            for (int r = 0; r < 4; ++r) {
                const float gi = acc[0][u][r];
                const float gf = acc[1][u][r];
                const float gg = acc[2][u][r];
                const float go = acc[3][u][r];
                const float si = 1.0f / (1.0f + exp2f(gi * -1.44269504f));
                const float sf = 1.0f / (1.0f + exp2f(gf * -1.44269504f));
                const float so = 1.0f / (1.0f + exp2f(go * -1.44269504f));
                const float tg = 2.0f / (1.0f + exp2f(gg * -2.88539008f)) - 1.0f;
                const float cn = sf * cst[u][r] + si * tg;
                const float th = 2.0f / (1.0f + exp2f(cn * -2.88539008f)) - 1.0f;
                cst[u][r] = cn;
                hq[u][r] = so * th;
            }

        __syncthreads();   /* all reads of a_lds done */

#pragma unroll
        for (int u = 0; u < 2; ++u) {
            short4v pk;
#pragma unroll
            for (int r = 0; r < 4; ++r) pk[r] = f2bf(hq[u][r]);
            *(short4v*)&a_lds[l15 * 256 + wv * 32 + u * 16 + lk * 4] = pk;
        }
        __syncthreads();
    }

    /* final tag projection for the last h */
    if (wv == 0) {
        const int tlast = dir ? 0 : (T_LEN - 1);
        float4v facc = {0.f, 0.f, 0.f, 0.f};
#pragma unroll
        for (int ks = 0; ks < 8; ++ks) {
            const short8 lf = lp[ks * 64 + lane];
            const short8 bfr = LDA(ks);
            facc = __builtin_amdgcn_mfma_f32_16x16x32_bf16(lf, bfr, facc, 0, 0, 0);
        }
#pragma unroll
        for (int r = 0; r < 4; ++r) {
            const int tag = lk * 4 + r;
            if (tag < TAGS)
                fout[((size_t)tlast * BATCH + b0 + l15) * TAGS + tag] = facc[r];
        }
    }
}

/* ---- CRF forward + gold, with t+1 emission prefetch ---- */
__launch_bounds__(320)
__global__ void crf_kernel(const float* __restrict__ ff, const float* __restrict__ fb,
                           const int* __restrict__ labels, const float* __restrict__ lin_b,
                           const float* __restrict__ trans, float* __restrict__ nll)
{
    const int tid = threadIdx.x;
    const int bl = tid / TAGS;
    const int tg = tid % TAGS;
    const int b = blockIdx.x * 32 + bl;

    __shared__ float fv[32][TAGS];
    __shared__ float tr[TAGS][TAGS];
    __shared__ float lb[TAGS];
    __shared__ float fs[32];
    __shared__ float gp[32][TAGS];

    if (tid < TAGS * TAGS) tr[tid / TAGS][tid % TAGS] = trans[tid];
    if (tid < TAGS) lb[tid] = lin_b[tid];
    fv[bl][tg] = (tg == START_TAG) ? 0.0f : NEG_INF;
    __syncthreads();

    const float myb = lb[tg];
    const float* pf = ff + (size_t)b * TAGS + tg;
    const float* pb = fb + (size_t)b * TAGS + tg;
    const size_t stride = (size_t)BATCH * TAGS;

    float cf = pf[0], cb = pb[0];
    for (int t = 0; t < T_LEN; ++t) {
        float nf = 0.0f, nb = 0.0f;
        if (t + 1 < T_LEN) {                       /* prefetch next emissions */
            nf = pf[(size_t)(t + 1) * stride];
            nb = pb[(size_t)(t + 1) * stride];
        }
        float v[TAGS];
#pragma unroll
        for (int p = 0; p < TAGS; ++p) v[p] = fv[bl][p] + tr[tg][p];
        float m = v[0];
#pragma unroll
        for (int p = 1; p < TAGS; ++p) m = fmaxf(m, v[p]);
        float ssum = 0.0f;
#pragma unroll
        for (int p = 0; p < TAGS; ++p) ssum += expf(v[p] - m);
        const float nv = m + logf(ssum) + cf + cb + myb;
        __syncthreads();
        fv[bl][tg] = nv;
        __syncthreads();
        cf = nf; cb = nb;
    }

    if (tg == 0) {
        float m = NEG_INF;
        float v[TAGS];
#pragma unroll
        for (int p = 0; p < TAGS; ++p) {
            v[p] = fv[bl][p] + tr[STOP_TAG][p];
            m = fmaxf(m, v[p]);
        }
        float ssum = 0.0f;
#pragma unroll
        for (int p = 0; p < TAGS; ++p) ssum += expf(v[p] - m);
        fs[bl] = m + logf(ssum);
    }

    float gpart = 0.0f;
    for (int t = tg; t < T_LEN; t += TAGS) {
        const int lab = labels[t * BATCH + b];
        const int prev = (t == 0) ? START_TAG : labels[(t - 1) * BATCH + b];
        const size_t base = ((size_t)t * BATCH + b) * TAGS;
        gpart += ff[base + lab] + fb[base + lab] + lb[lab] + tr[lab][prev];
    }
    gp[bl][tg] = gpart;
    __syncthreads();

    if (tg == 0) {
        float g = 0.0f;
#pragma unroll
        for (int p = 0; p < TAGS; ++p) g += gp[bl][p];
        g += tr[STOP_TAG][labels[(T_LEN - 1) * BATCH + b]];
        nll[b] = fs[bl] - g;
    }
}

__global__ void reduce_kernel(const float* __restrict__ nll, float* __restrict__ out)
{
    __shared__ float sdata[BATCH];
    const int tid = threadIdx.x;
    sdata[tid] = nll[tid];
    __syncthreads();
    for (int s = BATCH / 2; s > 0; s >>= 1) {
        if (tid < s) sdata[tid] += sdata[tid + s];
        __syncthreads();
    }
    if (tid == 0) out[0] = sdata[0] / (float)BATCH;
}

extern "C" void kernel_launch(void* const* d_in, const int* in_sizes, int n_in,
                              void* d_out, int out_size, void* d_ws, size_t ws_size,
                              hipStream_t stream)
{
    const float* features = (const float*)d_in[0];
    const int*   labels   = (const int*)d_in[1];
    const float* w_ih_f = (const float*)d_in[3];
    const float* w_hh_f = (const float*)d_in[4];
    const float* b_f    = (const float*)d_in[5];
    const float* w_ih_b = (const float*)d_in[6];
    const float* w_hh_b = (const float*)d_in[7];
    const float* b_b    = (const float*)d_in[8];
    const float* lin_w  = (const float*)d_in[9];
    const float* lin_b  = (const float*)d_in[10];
    const float* trans  = (const float*)d_in[11];

    float* ws = (float*)d_ws;
    short* wsS = (short*)(ws + WS_SHORTF);
    float* out = (float*)d_out;

    prep_w2<<<(2 * 8 * 88 * 64 + 255) / 256, 256, 0, stream>>>(
        w_ih_f, w_hh_f, b_f, w_ih_b, w_hh_b, b_b, wsS);
    prep_l<<<4, 256, 0, stream>>>(lin_w, wsS + LP_OFF);
    prep_x<<<(T_LEN * BATCH * 9 + 255) / 256, 256, 0, stream>>>(features, wsS + XP_OFF);

    bilstm_pers<<<32, 512, 0, stream>>>(wsS, wsS + XP_OFF, wsS + LP_OFF,
                                        ws + WS_FF, ws + WS_FB);

    crf_kernel<<<8, 320, 0, stream>>>(ws + WS_FF, ws + WS_FB, labels, lin_b, trans, ws + WS_NLL);
    reduce_kernel<<<1, BATCH, 0, stream>>>(ws + WS_NLL, out);
}